// Round 5
// baseline (71.214 us; speedup 1.0000x reference)
//
#include <hip/hip_runtime.h>

#define D 4096
#define BLOCK 256
#define NROWS (8 * 2048)
#define CAP 256
#define PADV (-3.0e38f)

typedef float v4f __attribute__((ext_vector_type(4)));

__global__ __launch_bounds__(BLOCK, 8) void sparsemax_kernel(
    const float* __restrict__ x, float* __restrict__ out) {
    __shared__ float s_red[8];
    __shared__ float s_act[CAP];
    __shared__ int s_cnt;

    const int row = blockIdx.x;
    const int t = threadIdx.x;
    const int wave = t >> 6;
    const int lane = t & 63;

    const v4f* __restrict__ xr =
        reinterpret_cast<const v4f*>(x + (size_t)row * D);
    v4f* __restrict__ outr = reinterpret_cast<v4f*>(out + (size_t)row * D);

    // Pass 1: load 16 elems/thread (coalesced 16B), thread-local max.
    // Regular (caching) loads: we WANT x resident in L3 across replays.
    v4f v[4];
    float tmax = PADV;
    #pragma unroll
    for (int j = 0; j < 4; ++j) {
        v[j] = xr[t + j * BLOCK];
        tmax = fmaxf(tmax, fmaxf(fmaxf(v[j].x, v[j].y), fmaxf(v[j].z, v[j].w)));
    }

    if (t == 0) s_cnt = 0;

    // Block max: wave butterfly + 4-slot LDS combine.
    #pragma unroll
    for (int m = 1; m < 64; m <<= 1)
        tmax = fmaxf(tmax, __shfl_xor(tmax, m, 64));
    if (lane == 0) s_red[wave] = tmax;
    __syncthreads();  // also publishes s_cnt = 0
    const float rmax = fmaxf(fmaxf(s_red[0], s_red[1]), fmaxf(s_red[2], s_red[3]));

    // tau* >= rmax - 1 (since sum of (x - tau*)_+ = 1 >= rmax - tau*),
    // and tau* < rmax. So {x > rmax-1} is a superset of the support.
    const float tau0 = rmax - 1.0f;

    // Pass 2: compact candidates (x > tau0) into LDS (~16-40 expected),
    // and accumulate their sum (psum) = Michelot iteration 0 fused in.
    float psum = 0.0f, dummy = 0.0f;
    #pragma unroll
    for (int j = 0; j < 4; ++j) {
        const float e0 = v[j].x, e1 = v[j].y, e2 = v[j].z, e3 = v[j].w;
        if (e0 > tau0) { psum += e0; int i = atomicAdd(&s_cnt, 1); if (i < CAP) s_act[i] = e0; }
        if (e1 > tau0) { psum += e1; int i = atomicAdd(&s_cnt, 1); if (i < CAP) s_act[i] = e1; }
        if (e2 > tau0) { psum += e2; int i = atomicAdd(&s_cnt, 1); if (i < CAP) s_act[i] = e2; }
        if (e3 > tau0) { psum += e3; int i = atomicAdd(&s_cnt, 1); if (i < CAP) s_act[i] = e3; }
    }
    #pragma unroll
    for (int m = 1; m < 64; m <<= 1) psum += __shfl_xor(psum, m, 64);
    if (lane == 0) s_red[4 + wave] = psum;
    __syncthreads();
    const int cnt0 = s_cnt;  // uniform across block
    const float sum0 = s_red[4] + s_red[5] + s_red[6] + s_red[7];

    // Michelot iteration 0 result: active set == candidate set.
    float tau = (sum0 - 1.0f) / (float)cnt0;
    float k_prev = (float)cnt0;

    if (cnt0 <= 32) {
        // Typical path. Duplicate the list into both 32-lane halves so the
        // butterfly needs only masks 1..16 (each half reduces identically ->
        // identical tau in all lanes, no divergence).
        const int l5 = lane & 31;
        const float a = (l5 < cnt0) ? s_act[l5] : PADV;
        for (int it = 0; it < 40; ++it) {
            float sum = 0.0f, cnt = 0.0f;
            if (a > tau) { sum = a; cnt = 1.0f; }
            #pragma unroll
            for (int m = 1; m < 32; m <<= 1) {
                sum += __shfl_xor(sum, m, 64);
                cnt += __shfl_xor(cnt, m, 64);
            }
            if (cnt == k_prev) break;   // active set stable -> tau final
            tau = (sum - 1.0f) / cnt;   // cnt >= 1 (rmax always active)
            k_prev = cnt;
        }
    } else if (cnt0 <= CAP) {
        // Wave-redundant Michelot over up to 256 candidates; no barriers.
        const float a0 = (lane + 0   < cnt0) ? s_act[lane + 0]   : PADV;
        const float a1 = (lane + 64  < cnt0) ? s_act[lane + 64]  : PADV;
        const float a2 = (lane + 128 < cnt0) ? s_act[lane + 128] : PADV;
        const float a3 = (lane + 192 < cnt0) ? s_act[lane + 192] : PADV;
        for (int it = 0; it < 48; ++it) {
            float sum = 0.0f, cnt = 0.0f;
            if (a0 > tau) { sum += a0; cnt += 1.0f; }
            if (a1 > tau) { sum += a1; cnt += 1.0f; }
            if (a2 > tau) { sum += a2; cnt += 1.0f; }
            if (a3 > tau) { sum += a3; cnt += 1.0f; }
            #pragma unroll
            for (int m = 1; m < 64; m <<= 1) {
                sum += __shfl_xor(sum, m, 64);
                cnt += __shfl_xor(cnt, m, 64);
            }
            if (cnt == k_prev) break;
            tau = (sum - 1.0f) / cnt;
            k_prev = cnt;
        }
    } else {
        // Fallback (never hit for N(0,1) data): block-wide Michelot over the
        // full register tile. tau/k_prev from the fused iteration 0 are still
        // valid (psum/s_cnt counted ALL candidates, CAP only limits storage).
        for (int it = 0; it < 64; ++it) {
            float sum = 0.0f, cnt = 0.0f;
            #pragma unroll
            for (int j = 0; j < 4; ++j) {
                if (v[j].x > tau) { sum += v[j].x; cnt += 1.0f; }
                if (v[j].y > tau) { sum += v[j].y; cnt += 1.0f; }
                if (v[j].z > tau) { sum += v[j].z; cnt += 1.0f; }
                if (v[j].w > tau) { sum += v[j].w; cnt += 1.0f; }
            }
            #pragma unroll
            for (int m = 1; m < 64; m <<= 1) {
                sum += __shfl_xor(sum, m, 64);
                cnt += __shfl_xor(cnt, m, 64);
            }
            if (lane == 0) { s_red[wave * 2] = sum; s_red[wave * 2 + 1] = cnt; }
            __syncthreads();
            sum = s_red[0] + s_red[2] + s_red[4] + s_red[6];
            cnt = s_red[1] + s_red[3] + s_red[5] + s_red[7];
            __syncthreads();
            if (cnt == k_prev) break;
            tau = (sum - 1.0f) / cnt;
            k_prev = cnt;
        }
    }

    // Pass 3: out = max(x - tau, 0). Nontemporal stores: output is
    // write-once, never re-read -> don't evict x from L3.
    #pragma unroll
    for (int j = 0; j < 4; ++j) {
        v4f o;
        o.x = fmaxf(v[j].x - tau, 0.0f);
        o.y = fmaxf(v[j].y - tau, 0.0f);
        o.z = fmaxf(v[j].z - tau, 0.0f);
        o.w = fmaxf(v[j].w - tau, 0.0f);
        __builtin_nontemporal_store(o, &outr[t + j * BLOCK]);
    }
}

extern "C" void kernel_launch(void* const* d_in, const int* in_sizes, int n_in,
                              void* d_out, int out_size, void* d_ws, size_t ws_size,
                              hipStream_t stream) {
    const float* x = (const float*)d_in[0];
    float* out = (float*)d_out;
    sparsemax_kernel<<<NROWS, BLOCK, 0, stream>>>(x, out);
}

// Round 6
// 69.952 us; speedup vs baseline: 1.0180x; 1.0180x over previous
//
#include <hip/hip_runtime.h>

#define D 4096
#define BLOCK 256
#define NROWS (8 * 2048)
#define CAP 256
#define PADV (-3.0e38f)

typedef float v4f __attribute__((ext_vector_type(4)));

// R4 kernel (69.9 us), reverted from R5's fused-iter0 variant (71.2 us):
// the Michelot chain is latency-hidden by 8 resident blocks/CU, so chain
// shortening was neutral; keep the simpler proven version.
__global__ __launch_bounds__(BLOCK, 8) void sparsemax_kernel(
    const float* __restrict__ x, float* __restrict__ out) {
    __shared__ float s_red[8];
    __shared__ float s_act[CAP];
    __shared__ int s_cnt;

    const int row = blockIdx.x;
    const int t = threadIdx.x;
    const int wave = t >> 6;
    const int lane = t & 63;

    const v4f* __restrict__ xr =
        reinterpret_cast<const v4f*>(x + (size_t)row * D);
    v4f* __restrict__ outr = reinterpret_cast<v4f*>(out + (size_t)row * D);

    // Pass 1: load 16 elems/thread (coalesced 16B), thread-local max.
    // Regular (caching) loads: we WANT x resident in L3 across replays.
    v4f v[4];
    float tmax = PADV;
    #pragma unroll
    for (int j = 0; j < 4; ++j) {
        v[j] = xr[t + j * BLOCK];
        tmax = fmaxf(tmax, fmaxf(fmaxf(v[j].x, v[j].y), fmaxf(v[j].z, v[j].w)));
    }

    if (t == 0) s_cnt = 0;

    // Block max: wave butterfly + 4-slot LDS combine.
    #pragma unroll
    for (int m = 1; m < 64; m <<= 1)
        tmax = fmaxf(tmax, __shfl_xor(tmax, m, 64));
    if (lane == 0) s_red[wave] = tmax;
    __syncthreads();  // also publishes s_cnt = 0
    const float rmax = fmaxf(fmaxf(s_red[0], s_red[1]), fmaxf(s_red[2], s_red[3]));

    // tau* >= rmax - 1 (since sum of (x - tau*)_+ = 1 >= rmax - tau*),
    // and tau* < rmax. So {x > rmax-1} is a superset of the support.
    const float tau0 = rmax - 1.0f;

    // Pass 2: compact candidates (x > tau0) into LDS (~16-40 expected).
    #pragma unroll
    for (int j = 0; j < 4; ++j) {
        const float e0 = v[j].x, e1 = v[j].y, e2 = v[j].z, e3 = v[j].w;
        if (e0 > tau0) { int i = atomicAdd(&s_cnt, 1); if (i < CAP) s_act[i] = e0; }
        if (e1 > tau0) { int i = atomicAdd(&s_cnt, 1); if (i < CAP) s_act[i] = e1; }
        if (e2 > tau0) { int i = atomicAdd(&s_cnt, 1); if (i < CAP) s_act[i] = e2; }
        if (e3 > tau0) { int i = atomicAdd(&s_cnt, 1); if (i < CAP) s_act[i] = e3; }
    }
    __syncthreads();
    const int cnt0 = s_cnt;  // uniform across block

    float tau = tau0;
    if (cnt0 <= CAP) {
        // Every wave redundantly runs Michelot on the compacted list:
        // no barriers, wave-local shuffles only. Identical fp sequence in
        // each wave -> identical tau.
        float a0 = (lane + 0   < cnt0) ? s_act[lane + 0]   : PADV;
        float a1 = (lane + 64  < cnt0) ? s_act[lane + 64]  : PADV;
        float a2 = (lane + 128 < cnt0) ? s_act[lane + 128] : PADV;
        float a3 = (lane + 192 < cnt0) ? s_act[lane + 192] : PADV;
        float k_prev = 1.0e30f;  // sentinel: first iteration never "done"
        for (int it = 0; it < 48; ++it) {
            float sum = 0.0f, cnt = 0.0f;
            if (a0 > tau) { sum += a0; cnt += 1.0f; }
            if (a1 > tau) { sum += a1; cnt += 1.0f; }
            if (a2 > tau) { sum += a2; cnt += 1.0f; }
            if (a3 > tau) { sum += a3; cnt += 1.0f; }
            #pragma unroll
            for (int m = 1; m < 64; m <<= 1) {
                sum += __shfl_xor(sum, m, 64);
                cnt += __shfl_xor(cnt, m, 64);
            }
            if (cnt == k_prev) break;   // active set stable -> tau is final
            tau = (sum - 1.0f) / cnt;   // cnt >= 1 always (rmax stays active)
            k_prev = cnt;
        }
    } else {
        // Fallback (never hit for N(0,1) data): block-wide Michelot from tau0
        // over the full register tile.
        float k_prev = 1.0e30f;
        for (int it = 0; it < 64; ++it) {
            float sum = 0.0f, cnt = 0.0f;
            #pragma unroll
            for (int j = 0; j < 4; ++j) {
                if (v[j].x > tau) { sum += v[j].x; cnt += 1.0f; }
                if (v[j].y > tau) { sum += v[j].y; cnt += 1.0f; }
                if (v[j].z > tau) { sum += v[j].z; cnt += 1.0f; }
                if (v[j].w > tau) { sum += v[j].w; cnt += 1.0f; }
            }
            #pragma unroll
            for (int m = 1; m < 64; m <<= 1) {
                sum += __shfl_xor(sum, m, 64);
                cnt += __shfl_xor(cnt, m, 64);
            }
            if (lane == 0) { s_red[wave * 2] = sum; s_red[wave * 2 + 1] = cnt; }
            __syncthreads();
            sum = s_red[0] + s_red[2] + s_red[4] + s_red[6];
            cnt = s_red[1] + s_red[3] + s_red[5] + s_red[7];
            __syncthreads();
            if (cnt == k_prev) break;
            tau = (sum - 1.0f) / cnt;
            k_prev = cnt;
        }
    }

    // Pass 3: out = max(x - tau, 0). Nontemporal stores: output is
    // write-once, never re-read -> don't evict x from L3.
    #pragma unroll
    for (int j = 0; j < 4; ++j) {
        v4f o;
        o.x = fmaxf(v[j].x - tau, 0.0f);
        o.y = fmaxf(v[j].y - tau, 0.0f);
        o.z = fmaxf(v[j].z - tau, 0.0f);
        o.w = fmaxf(v[j].w - tau, 0.0f);
        __builtin_nontemporal_store(o, &outr[t + j * BLOCK]);
    }
}

extern "C" void kernel_launch(void* const* d_in, const int* in_sizes, int n_in,
                              void* d_out, int out_size, void* d_ws, size_t ws_size,
                              hipStream_t stream) {
    const float* x = (const float*)d_in[0];
    float* out = (float*)d_out;
    sparsemax_kernel<<<NROWS, BLOCK, 0, stream>>>(x, out);
}